// Round 3
// baseline (3075.658 us; speedup 1.0000x reference)
//
#include <hip/hip_runtime.h>
#include <hip/hip_bf16.h>

// Problem constants: B=4, T=2048, D=512, H=8, DK=64
#define T_SEQ 2048
#define N_TOK 4194304   // 4 * 2048 * 512 elements per [B,T,D] tensor

// Inputs: FLOAT32. Output: FLOAT32 (reference output dtype), (e2s, s2e) concat.
// Intermediates Q/K/V/AO: bf16 in d_ws (24 MB; AO aliases Q).

__device__ __forceinline__ unsigned short f2b(float f) {
    __hip_bfloat16 h = __float2bfloat16(f);
    return *reinterpret_cast<unsigned short*>(&h);
}

__device__ __forceinline__ void unpack2(unsigned int v, float& lo, float& hi) {
    lo = __uint_as_float(v << 16);
    hi = __uint_as_float(v & 0xffff0000u);
}

// Load 8 consecutive bf16 (one int4) -> f32 dst[0..7]
__device__ __forceinline__ void load8bf(const unsigned short* __restrict__ p, float* dst) {
    const int4 v = *reinterpret_cast<const int4*>(p);
    float a, b;
    unpack2((unsigned int)v.x, a, b); dst[0] = a; dst[1] = b;
    unpack2((unsigned int)v.y, a, b); dst[2] = a; dst[3] = b;
    unpack2((unsigned int)v.z, a, b); dst[4] = a; dst[5] = b;
    unpack2((unsigned int)v.w, a, b); dst[6] = a; dst[7] = b;
}

// Load 8 consecutive f32 (two float4) -> dst[0..7]
__device__ __forceinline__ void load8f(const float* __restrict__ p, float* dst) {
    const float4 v0 = *reinterpret_cast<const float4*>(p);
    const float4 v1 = *reinterpret_cast<const float4*>(p + 4);
    dst[0] = v0.x; dst[1] = v0.y; dst[2] = v0.z; dst[3] = v0.w;
    dst[4] = v1.x; dst[5] = v1.y; dst[6] = v1.z; dst[7] = v1.w;
}

// Shared GEMM main loop: C[m,n] = sum_k A[m,k] * W[n,k], 64x64 tile, BK=32,
// 256 threads, 4x4 micro-tile. LOAD_A provided per-kernel; epilogue per-kernel.
#define GEMM_MAIN                                                              \
    __shared__ float As[64][33];                                               \
    __shared__ float Ws[64][33];                                               \
    const int tid = threadIdx.x;                                               \
    const int n0 = blockIdx.x * 64;                                            \
    const int m0 = blockIdx.y * 64;                                            \
    const int tx = tid & 15, ty = tid >> 4;                                    \
    const int lrow = tid >> 2;                                                 \
    const int lcol = (tid & 3) * 8;                                            \
    float acc[4][4] = {};                                                      \
    for (int k0 = 0; k0 < 512; k0 += 32) {                                     \
        LOAD_A(A + (size_t)(m0 + lrow) * 512 + k0 + lcol, &As[lrow][lcol]);    \
        load8f(W + (size_t)(n0 + lrow) * 512 + k0 + lcol, &Ws[lrow][lcol]);    \
        __syncthreads();                                                       \
        _Pragma("unroll 8")                                                    \
        for (int kk = 0; kk < 32; ++kk) {                                      \
            const float a0 = As[ty * 4 + 0][kk];                               \
            const float a1 = As[ty * 4 + 1][kk];                               \
            const float a2 = As[ty * 4 + 2][kk];                               \
            const float a3 = As[ty * 4 + 3][kk];                               \
            const float b0 = Ws[tx * 4 + 0][kk];                               \
            const float b1 = Ws[tx * 4 + 1][kk];                               \
            const float b2 = Ws[tx * 4 + 2][kk];                               \
            const float b3 = Ws[tx * 4 + 3][kk];                               \
            acc[0][0] = fmaf(a0, b0, acc[0][0]);                               \
            acc[0][1] = fmaf(a0, b1, acc[0][1]);                               \
            acc[0][2] = fmaf(a0, b2, acc[0][2]);                               \
            acc[0][3] = fmaf(a0, b3, acc[0][3]);                               \
            acc[1][0] = fmaf(a1, b0, acc[1][0]);                               \
            acc[1][1] = fmaf(a1, b1, acc[1][1]);                               \
            acc[1][2] = fmaf(a1, b2, acc[1][2]);                               \
            acc[1][3] = fmaf(a1, b3, acc[1][3]);                               \
            acc[2][0] = fmaf(a2, b0, acc[2][0]);                               \
            acc[2][1] = fmaf(a2, b1, acc[2][1]);                               \
            acc[2][2] = fmaf(a2, b2, acc[2][2]);                               \
            acc[2][3] = fmaf(a2, b3, acc[2][3]);                               \
            acc[3][0] = fmaf(a3, b0, acc[3][0]);                               \
            acc[3][1] = fmaf(a3, b1, acc[3][1]);                               \
            acc[3][2] = fmaf(a3, b2, acc[3][2]);                               \
            acc[3][3] = fmaf(a3, b3, acc[3][3]);                               \
        }                                                                      \
        __syncthreads();                                                       \
    }

// Q/K/V projection: A fp32, W fp32, C bf16, scaled by alpha.
__global__ __launch_bounds__(256)
void gemm_qkv(const float* __restrict__ A,
              const float* __restrict__ W,
              unsigned short* __restrict__ C,
              float alpha)
{
#define LOAD_A load8f
    GEMM_MAIN
#undef LOAD_A
    #pragma unroll
    for (int i = 0; i < 4; ++i) {
        const int m = m0 + ty * 4 + i;
        ushort4 o;
        o.x = f2b(acc[i][0] * alpha);
        o.y = f2b(acc[i][1] * alpha);
        o.z = f2b(acc[i][2] * alpha);
        o.w = f2b(acc[i][3] * alpha);
        *reinterpret_cast<ushort4*>(C + (size_t)m * 512 + n0 + tx * 4) = o;
    }
}

// Output projection: A bf16 (AO), W fp32, C fp32.
__global__ __launch_bounds__(256)
void gemm_out(const unsigned short* __restrict__ A,
              const float* __restrict__ W,
              float* __restrict__ C)
{
#define LOAD_A load8bf
    GEMM_MAIN
#undef LOAD_A
    #pragma unroll
    for (int i = 0; i < 4; ++i) {
        const int m = m0 + ty * 4 + i;
        float4 o;
        o.x = acc[i][0];
        o.y = acc[i][1];
        o.z = acc[i][2];
        o.w = acc[i][3];
        *reinterpret_cast<float4*>(C + (size_t)m * 512 + n0 + tx * 4) = o;
    }
}

// Flash attention, one block per (b, h, 64-row q-tile).
// Q pre-scaled by 1.5/8. mask: int32 [B, T_SEQ], 0 => logit -1e30.
// Q/K/V/AO: [B, T, 512] bf16, head h at cols [h*64, h*64+64).
// AO may alias Q (each block loads its Q tile to LDS before its AO write).
__global__ __launch_bounds__(256)
void attn64(const unsigned short* __restrict__ Q,
            const unsigned short* __restrict__ K,
            const unsigned short* __restrict__ V,
            const int* __restrict__ mask,
            unsigned short* __restrict__ AO)
{
    __shared__ float Qs[64][65];
    __shared__ float KSs[64][65];   // K tile; reused for S/P after scores
    __shared__ float Vs[64][65];
    __shared__ int   msk[64];

    const int tid = threadIdx.x;
    const int qt = blockIdx.x;          // 0..31
    const int bh = blockIdx.y;          // 0..31
    const int b = bh >> 3, h = bh & 7;
    const size_t base = (size_t)b * T_SEQ * 512 + h * 64;

    const int lrow = tid >> 2;          // loader row 0..63
    const int lcol = (tid & 3) * 16;    // loader col 0,16,32,48
    const int tx = tid & 15, ty = tid >> 4;   // score-phase 4x4 tile coords
    const int r  = tid >> 2;            // softmax / O-phase row
    const int q4 = tid & 3;
    const int d0 = q4 * 16;             // O-phase dim offset

    {
        const unsigned short* p = Q + base + (size_t)(qt * 64 + lrow) * 512 + lcol;
        load8bf(p,     &Qs[lrow][lcol]);
        load8bf(p + 8, &Qs[lrow][lcol + 8]);
    }

    float m_old = -INFINITY, l_old = 0.0f;
    float O[16] = {};

    for (int kt = 0; kt < 32; ++kt) {
        {
            const unsigned short* pk = K + base + (size_t)(kt * 64 + lrow) * 512 + lcol;
            const unsigned short* pv = V + base + (size_t)(kt * 64 + lrow) * 512 + lcol;
            load8bf(pk,     &KSs[lrow][lcol]);
            load8bf(pk + 8, &KSs[lrow][lcol + 8]);
            load8bf(pv,     &Vs[lrow][lcol]);
            load8bf(pv + 8, &Vs[lrow][lcol + 8]);
            if (tid < 64) msk[tid] = mask[b * T_SEQ + kt * 64 + tid];
        }
        __syncthreads();

        // scores = Q K^T (Q pre-scaled)
        float acc[4][4] = {};
        #pragma unroll 8
        for (int kk = 0; kk < 64; ++kk) {
            const float a0 = Qs[ty * 4 + 0][kk];
            const float a1 = Qs[ty * 4 + 1][kk];
            const float a2 = Qs[ty * 4 + 2][kk];
            const float a3 = Qs[ty * 4 + 3][kk];
            const float b0 = KSs[tx * 4 + 0][kk];
            const float b1 = KSs[tx * 4 + 1][kk];
            const float b2 = KSs[tx * 4 + 2][kk];
            const float b3 = KSs[tx * 4 + 3][kk];
            acc[0][0] = fmaf(a0, b0, acc[0][0]);
            acc[0][1] = fmaf(a0, b1, acc[0][1]);
            acc[0][2] = fmaf(a0, b2, acc[0][2]);
            acc[0][3] = fmaf(a0, b3, acc[0][3]);
            acc[1][0] = fmaf(a1, b0, acc[1][0]);
            acc[1][1] = fmaf(a1, b1, acc[1][1]);
            acc[1][2] = fmaf(a1, b2, acc[1][2]);
            acc[1][3] = fmaf(a1, b3, acc[1][3]);
            acc[2][0] = fmaf(a2, b0, acc[2][0]);
            acc[2][1] = fmaf(a2, b1, acc[2][1]);
            acc[2][2] = fmaf(a2, b2, acc[2][2]);
            acc[2][3] = fmaf(a2, b3, acc[2][3]);
            acc[3][0] = fmaf(a3, b0, acc[3][0]);
            acc[3][1] = fmaf(a3, b1, acc[3][1]);
            acc[3][2] = fmaf(a3, b2, acc[3][2]);
            acc[3][3] = fmaf(a3, b3, acc[3][3]);
        }
        __syncthreads();   // everyone done reading K before S overwrites it

        #pragma unroll
        for (int i = 0; i < 4; ++i)
            #pragma unroll
            for (int j = 0; j < 4; ++j)
                KSs[ty * 4 + i][tx * 4 + j] = (msk[tx * 4 + j] != 0) ? acc[i][j] : -1e30f;
        __syncthreads();

        // online softmax, row r, 4 lanes/row
        float sv[16];
        float pm = -INFINITY;
        #pragma unroll
        for (int j = 0; j < 16; ++j) {
            sv[j] = KSs[r][q4 * 16 + j];
            pm = fmaxf(pm, sv[j]);
        }
        pm = fmaxf(pm, __shfl_xor(pm, 1));
        pm = fmaxf(pm, __shfl_xor(pm, 2));
        const float m_new = fmaxf(m_old, pm);
        const float alpha = __expf(m_old - m_new);
        float psum = 0.0f;
        #pragma unroll
        for (int j = 0; j < 16; ++j) {
            const float p = __expf(sv[j] - m_new);
            psum += p;
            KSs[r][q4 * 16 + j] = p;
        }
        psum += __shfl_xor(psum, 1);
        psum += __shfl_xor(psum, 2);
        l_old = alpha * l_old + psum;
        m_old = m_new;
        __syncthreads();

        // O = alpha*O + P @ V, row r, dims d0..d0+15
        #pragma unroll
        for (int j = 0; j < 16; ++j) O[j] *= alpha;
        #pragma unroll 4
        for (int c = 0; c < 64; ++c) {
            const float p = KSs[r][c];
            #pragma unroll
            for (int j = 0; j < 16; ++j)
                O[j] = fmaf(p, Vs[c][d0 + j], O[j]);
        }
        __syncthreads();
    }

    const float inv = 1.0f / l_old;
    unsigned short* po = AO + base + (size_t)(qt * 64 + r) * 512 + d0;
    #pragma unroll
    for (int s = 0; s < 4; ++s) {
        ushort4 o;
        o.x = f2b(O[s * 4 + 0] * inv);
        o.y = f2b(O[s * 4 + 1] * inv);
        o.z = f2b(O[s * 4 + 2] * inv);
        o.w = f2b(O[s * 4 + 3] * inv);
        reinterpret_cast<ushort4*>(po)[s] = o;
    }
}

extern "C" void kernel_launch(void* const* d_in, const int* in_sizes, int n_in,
                              void* d_out, int out_size, void* d_ws, size_t ws_size,
                              hipStream_t stream) {
    const float* skel = (const float*)d_in[0];
    const float* sens = (const float*)d_in[1];
    const int* mask_skel = (const int*)d_in[2];
    const int* mask_sens = (const int*)d_in[3];
    const float* Wq_s2e = (const float*)d_in[4];
    const float* Wk_e   = (const float*)d_in[5];
    const float* Wv_e   = (const float*)d_in[6];
    const float* Wq_e2s = (const float*)d_in[7];
    const float* Wk_s   = (const float*)d_in[8];
    const float* Wv_s   = (const float*)d_in[9];
    const float* Wo_s   = (const float*)d_in[10];
    const float* Wo_e   = (const float*)d_in[11];
    float* out = (float*)d_out;   // fp32: [e2s (4M floats)][s2e (4M floats)]

    unsigned short* Qw  = (unsigned short*)d_ws;   // also AO (aliased)
    unsigned short* Kw  = Qw + N_TOK;
    unsigned short* Vw  = Kw + N_TOK;

    const dim3 gg(8, 128);   // N/64 x M/64
    const dim3 ag(32, 32);   // q-tiles x (b*h)
    const float SCALE_Q = 0.1875f;   // 1.5 / sqrt(64)

    // ---- s2e: skel queries attend over sens kv -> output slot 1 ----
    gemm_qkv<<<gg, 256, 0, stream>>>(skel, Wq_s2e, Qw, SCALE_Q);
    gemm_qkv<<<gg, 256, 0, stream>>>(sens, Wk_e,  Kw, 1.0f);
    gemm_qkv<<<gg, 256, 0, stream>>>(sens, Wv_e,  Vw, 1.0f);
    attn64<<<ag, 256, 0, stream>>>(Qw, Kw, Vw, mask_sens, Qw);
    gemm_out<<<gg, 256, 0, stream>>>(Qw, Wo_e, out + N_TOK);

    // ---- e2s: sens queries attend over skel kv -> output slot 0 ----
    gemm_qkv<<<gg, 256, 0, stream>>>(sens, Wq_e2s, Qw, SCALE_Q);
    gemm_qkv<<<gg, 256, 0, stream>>>(skel, Wk_s,  Kw, 1.0f);
    gemm_qkv<<<gg, 256, 0, stream>>>(skel, Wv_s,  Vw, 1.0f);
    attn64<<<ag, 256, 0, stream>>>(Qw, Kw, Vw, mask_skel, Qw);
    gemm_out<<<gg, 256, 0, stream>>>(Qw, Wo_s, out);
}

// Round 4
// 1374.138 us; speedup vs baseline: 2.2382x; 2.2382x over previous
//
#include <hip/hip_runtime.h>
#include <hip/hip_bf16.h>

// Problem constants: B=4, T=2048, D=512, H=8, DK=64
#define T_SEQ 2048
#define N_TOK 4194304   // 4 * 2048 * 512 elements per [B,T,D] tensor

// Inputs: FLOAT32. Output: FLOAT32, (e2s, s2e) concat.
// Intermediates (d_ws, 24 MB): Qw bf16 [B,T,512] (aliased as AO), Kw bf16
// [B,T,512], Vt bf16 [B,512,T] (transposed V for MFMA B-frags).

typedef float f32x4  __attribute__((ext_vector_type(4)));
typedef short bf16x8 __attribute__((ext_vector_type(8)));

__device__ __forceinline__ unsigned short f2b(float f) {
    __hip_bfloat16 h = __float2bfloat16(f);
    return *reinterpret_cast<unsigned short*>(&h);
}

__device__ __forceinline__ void unpack2(unsigned int v, float& lo, float& hi) {
    lo = __uint_as_float(v << 16);
    hi = __uint_as_float(v & 0xffff0000u);
}

__device__ __forceinline__ void load8bf(const unsigned short* __restrict__ p, float* dst) {
    const int4 v = *reinterpret_cast<const int4*>(p);
    float a, b;
    unpack2((unsigned int)v.x, a, b); dst[0] = a; dst[1] = b;
    unpack2((unsigned int)v.y, a, b); dst[2] = a; dst[3] = b;
    unpack2((unsigned int)v.z, a, b); dst[4] = a; dst[5] = b;
    unpack2((unsigned int)v.w, a, b); dst[6] = a; dst[7] = b;
}

__device__ __forceinline__ void load8f(const float* __restrict__ p, float* dst) {
    const float4 v0 = *reinterpret_cast<const float4*>(p);
    const float4 v1 = *reinterpret_cast<const float4*>(p + 4);
    dst[0] = v0.x; dst[1] = v0.y; dst[2] = v0.z; dst[3] = v0.w;
    dst[4] = v1.x; dst[5] = v1.y; dst[6] = v1.z; dst[7] = v1.w;
}

// 8 bf16 (16B) global -> bf16x8 frag
__device__ __forceinline__ bf16x8 ldg8(const unsigned short* p) {
    union { int4 i; bf16x8 b; } u;
    u.i = *reinterpret_cast<const int4*>(p);
    return u.b;
}

// Shared VALU GEMM main loop: C[m,n] = sum_k A[m,k] * W[n,k], 64x64 tile,
// BK=32, 256 threads, 4x4 micro-tile.
#define GEMM_MAIN                                                              \
    __shared__ float As[64][33];                                               \
    __shared__ float Ws[64][33];                                               \
    const int tid = threadIdx.x;                                               \
    const int n0 = blockIdx.x * 64;                                            \
    const int m0 = blockIdx.y * 64;                                            \
    const int tx = tid & 15, ty = tid >> 4;                                    \
    const int lrow = tid >> 2;                                                 \
    const int lcol = (tid & 3) * 8;                                            \
    float acc[4][4] = {};                                                      \
    for (int k0 = 0; k0 < 512; k0 += 32) {                                     \
        LOAD_A(A + (size_t)(m0 + lrow) * 512 + k0 + lcol, &As[lrow][lcol]);    \
        load8f(W + (size_t)(n0 + lrow) * 512 + k0 + lcol, &Ws[lrow][lcol]);    \
        __syncthreads();                                                       \
        _Pragma("unroll 8")                                                    \
        for (int kk = 0; kk < 32; ++kk) {                                      \
            const float a0 = As[ty * 4 + 0][kk];                               \
            const float a1 = As[ty * 4 + 1][kk];                               \
            const float a2 = As[ty * 4 + 2][kk];                               \
            const float a3 = As[ty * 4 + 3][kk];                               \
            const float b0 = Ws[tx * 4 + 0][kk];                               \
            const float b1 = Ws[tx * 4 + 1][kk];                               \
            const float b2 = Ws[tx * 4 + 2][kk];                               \
            const float b3 = Ws[tx * 4 + 3][kk];                               \
            acc[0][0] = fmaf(a0, b0, acc[0][0]);                               \
            acc[0][1] = fmaf(a0, b1, acc[0][1]);                               \
            acc[0][2] = fmaf(a0, b2, acc[0][2]);                               \
            acc[0][3] = fmaf(a0, b3, acc[0][3]);                               \
            acc[1][0] = fmaf(a1, b0, acc[1][0]);                               \
            acc[1][1] = fmaf(a1, b1, acc[1][1]);                               \
            acc[1][2] = fmaf(a1, b2, acc[1][2]);                               \
            acc[1][3] = fmaf(a1, b3, acc[1][3]);                               \
            acc[2][0] = fmaf(a2, b0, acc[2][0]);                               \
            acc[2][1] = fmaf(a2, b1, acc[2][1]);                               \
            acc[2][2] = fmaf(a2, b2, acc[2][2]);                               \
            acc[2][3] = fmaf(a2, b3, acc[2][3]);                               \
            acc[3][0] = fmaf(a3, b0, acc[3][0]);                               \
            acc[3][1] = fmaf(a3, b1, acc[3][1]);                               \
            acc[3][2] = fmaf(a3, b2, acc[3][2]);                               \
            acc[3][3] = fmaf(a3, b3, acc[3][3]);                               \
        }                                                                      \
        __syncthreads();                                                       \
    }

// Q/K projection: A fp32, W fp32, C bf16 [token][512], scaled by alpha.
__global__ __launch_bounds__(256)
void gemm_qkv(const float* __restrict__ A,
              const float* __restrict__ W,
              unsigned short* __restrict__ C,
              float alpha)
{
#define LOAD_A load8f
    GEMM_MAIN
#undef LOAD_A
    #pragma unroll
    for (int i = 0; i < 4; ++i) {
        const int m = m0 + ty * 4 + i;
        ushort4 o;
        o.x = f2b(acc[i][0] * alpha);
        o.y = f2b(acc[i][1] * alpha);
        o.z = f2b(acc[i][2] * alpha);
        o.w = f2b(acc[i][3] * alpha);
        *reinterpret_cast<ushort4*>(C + (size_t)m * 512 + n0 + tx * 4) = o;
    }
}

// V projection with TRANSPOSED epilogue: Vt[b][n=512][t=2048] bf16.
__global__ __launch_bounds__(256)
void gemm_vt(const float* __restrict__ A,
             const float* __restrict__ W,
             unsigned short* __restrict__ Vt)
{
#define LOAD_A load8f
    GEMM_MAIN
#undef LOAD_A
    const int b  = m0 >> 11;         // token block -> batch
    const int t0 = (m0 & 2047) + ty * 4;
    #pragma unroll
    for (int j = 0; j < 4; ++j) {
        const int n = n0 + tx * 4 + j;
        ushort4 o;
        o.x = f2b(acc[0][j]);
        o.y = f2b(acc[1][j]);
        o.z = f2b(acc[2][j]);
        o.w = f2b(acc[3][j]);
        *reinterpret_cast<ushort4*>(Vt + ((size_t)(b * 512 + n)) * T_SEQ + t0) = o;
    }
}

// Output projection: A bf16 (AO), W fp32, C fp32.
__global__ __launch_bounds__(256)
void gemm_out(const unsigned short* __restrict__ A,
              const float* __restrict__ W,
              float* __restrict__ C)
{
#define LOAD_A load8bf
    GEMM_MAIN
#undef LOAD_A
    #pragma unroll
    for (int i = 0; i < 4; ++i) {
        const int m = m0 + ty * 4 + i;
        float4 o;
        o.x = acc[i][0];
        o.y = acc[i][1];
        o.z = acc[i][2];
        o.w = acc[i][3];
        *reinterpret_cast<float4*>(C + (size_t)m * 512 + n0 + tx * 4) = o;
    }
}

// MFMA flash attention. Block = 4 waves = one (b,h,64-row q-tile); wave owns
// 16 q rows. S^T = K·Q^T in C-layout (col=lane&15 => q), softmax via
// shfl_xor(16/32); P relayout C->A via wave-private LDS (no __syncthreads
// anywhere). V from pre-transposed Vt. Q pre-scaled by 1.5/8.
// AO may alias Q: each block reads only its own Q region (registers) before
// its only AO write to that same region.
__global__ __launch_bounds__(256)
void attn_mfma(const unsigned short* Q,
               const unsigned short* __restrict__ K,
               const unsigned short* __restrict__ Vt,
               const int* __restrict__ mask,
               unsigned short* AO)
{
    __shared__ short Pl[4][16][72];   // per-wave P scratch, pitch 72 bf16

    const int tid  = threadIdx.x;
    const int w    = tid >> 6;        // wave 0..3
    const int lane = tid & 63;
    const int nl   = lane & 15;
    const int quad = lane >> 4;
    const int qt = blockIdx.x;        // 0..31
    const int bh = blockIdx.y;        // 0..31
    const int b = bh >> 3, h = bh & 7;

    const size_t tb = (size_t)b * (T_SEQ * 512);

    // Q B-frags for q row = qt*64 + w*16 + nl (B-layout: n=lane&15, k=quad*8+j)
    const unsigned short* qp = Q + tb + (size_t)(qt * 64 + w * 16 + nl) * 512 + h * 64 + quad * 8;
    const bf16x8 qb0 = ldg8(qp);
    const bf16x8 qb1 = ldg8(qp + 32);

    const int* mrow = mask + b * T_SEQ;

    float m_run = -INFINITY, l_run = 0.0f;
    f32x4 o[4] = {};   // o[sd]: d = sd*16 + nl (col), q = quad*4 + reg (row)

    for (int kt = 0; kt < 32; ++kt) {
        // --- stage all global reads for this tile up front ---
        bf16x8 ka[4][2];   // A-frags of K: m=kv local, k=dk
        #pragma unroll
        for (int s = 0; s < 4; ++s) {
            const unsigned short* kp = K + tb + (size_t)(kt * 64 + s * 16 + nl) * 512 + h * 64 + quad * 8;
            ka[s][0] = ldg8(kp);
            ka[s][1] = ldg8(kp + 32);
        }
        bf16x8 vb[4][2];   // B-frags of V: n=d, k=kv
        #pragma unroll
        for (int sd = 0; sd < 4; ++sd) {
            const unsigned short* vp = Vt + ((size_t)(b * 512 + h * 64 + sd * 16 + nl)) * T_SEQ + kt * 64 + quad * 8;
            vb[sd][0] = ldg8(vp);
            vb[sd][1] = ldg8(vp + 32);
        }
        int4 mm[4];
        #pragma unroll
        for (int s = 0; s < 4; ++s)
            mm[s] = *reinterpret_cast<const int4*>(mrow + kt * 64 + s * 16 + quad * 4);

        // --- scores S^T[kv][q] ---
        float p[4][4];
        float mx = -INFINITY;
        #pragma unroll
        for (int s = 0; s < 4; ++s) {
            f32x4 z = {};
            z = __builtin_amdgcn_mfma_f32_16x16x32_bf16(ka[s][0], qb0, z, 0, 0, 0);
            z = __builtin_amdgcn_mfma_f32_16x16x32_bf16(ka[s][1], qb1, z, 0, 0, 0);
            p[s][0] = (mm[s].x != 0) ? z[0] : -1e30f;
            p[s][1] = (mm[s].y != 0) ? z[1] : -1e30f;
            p[s][2] = (mm[s].z != 0) ? z[2] : -1e30f;
            p[s][3] = (mm[s].w != 0) ? z[3] : -1e30f;
            #pragma unroll
            for (int r = 0; r < 4; ++r) mx = fmaxf(mx, p[s][r]);
        }

        // --- online softmax over kv (in-lane 16 + cross-quad) ---
        mx = fmaxf(mx, __shfl_xor(mx, 16));
        mx = fmaxf(mx, __shfl_xor(mx, 32));
        const float m_new = fmaxf(m_run, mx);
        const float al = __expf(m_run - m_new);
        float ps = 0.0f;
        #pragma unroll
        for (int s = 0; s < 4; ++s)
            #pragma unroll
            for (int r = 0; r < 4; ++r) {
                p[s][r] = __expf(p[s][r] - m_new);
                ps += p[s][r];
            }
        ps += __shfl_xor(ps, 16);
        ps += __shfl_xor(ps, 32);
        l_run = al * l_run + ps;
        m_run = m_new;

        // --- P: C-layout -> LDS [q][kv] (packed b64 writes, wave-private) ---
        #pragma unroll
        for (int s = 0; s < 4; ++s) {
            int2 pk;
            pk.x = ((int)f2b(p[s][1]) << 16) | (int)f2b(p[s][0]);
            pk.y = ((int)f2b(p[s][3]) << 16) | (int)f2b(p[s][2]);
            *reinterpret_cast<int2*>(&Pl[w][nl][s * 16 + quad * 4]) = pk;
        }

        // --- rescale O by alpha (alpha lives at lane q, O rows q=quad*4+r) ---
        const float a0 = __shfl(al, quad * 4 + 0);
        const float a1 = __shfl(al, quad * 4 + 1);
        const float a2 = __shfl(al, quad * 4 + 2);
        const float a3 = __shfl(al, quad * 4 + 3);
        #pragma unroll
        for (int sd = 0; sd < 4; ++sd) {
            o[sd][0] *= a0; o[sd][1] *= a1; o[sd][2] *= a2; o[sd][3] *= a3;
        }

        // --- P A-frags from LDS, then O += P · V ---
        const bf16x8 pa0 = *reinterpret_cast<const bf16x8*>(&Pl[w][nl][quad * 8]);
        const bf16x8 pa1 = *reinterpret_cast<const bf16x8*>(&Pl[w][nl][32 + quad * 8]);
        #pragma unroll
        for (int sd = 0; sd < 4; ++sd) {
            o[sd] = __builtin_amdgcn_mfma_f32_16x16x32_bf16(pa0, vb[sd][0], o[sd], 0, 0, 0);
            o[sd] = __builtin_amdgcn_mfma_f32_16x16x32_bf16(pa1, vb[sd][1], o[sd], 0, 0, 0);
        }
    }

    // --- epilogue: AO[q][d] = O/l, bf16 ---
    const float i0 = 1.0f / __shfl(l_run, quad * 4 + 0);
    const float i1 = 1.0f / __shfl(l_run, quad * 4 + 1);
    const float i2 = 1.0f / __shfl(l_run, quad * 4 + 2);
    const float i3 = 1.0f / __shfl(l_run, quad * 4 + 3);
    unsigned short* ob = AO + tb + (size_t)(qt * 64 + w * 16 + quad * 4) * 512 + h * 64 + nl;
    #pragma unroll
    for (int sd = 0; sd < 4; ++sd) {
        ob[0 * 512 + sd * 16] = f2b(o[sd][0] * i0);
        ob[1 * 512 + sd * 16] = f2b(o[sd][1] * i1);
        ob[2 * 512 + sd * 16] = f2b(o[sd][2] * i2);
        ob[3 * 512 + sd * 16] = f2b(o[sd][3] * i3);
    }
}

extern "C" void kernel_launch(void* const* d_in, const int* in_sizes, int n_in,
                              void* d_out, int out_size, void* d_ws, size_t ws_size,
                              hipStream_t stream) {
    const float* skel = (const float*)d_in[0];
    const float* sens = (const float*)d_in[1];
    const int* mask_skel = (const int*)d_in[2];
    const int* mask_sens = (const int*)d_in[3];
    const float* Wq_s2e = (const float*)d_in[4];
    const float* Wk_e   = (const float*)d_in[5];
    const float* Wv_e   = (const float*)d_in[6];
    const float* Wq_e2s = (const float*)d_in[7];
    const float* Wk_s   = (const float*)d_in[8];
    const float* Wv_s   = (const float*)d_in[9];
    const float* Wo_s   = (const float*)d_in[10];
    const float* Wo_e   = (const float*)d_in[11];
    float* out = (float*)d_out;   // fp32: [e2s (4M)][s2e (4M)]

    unsigned short* Qw  = (unsigned short*)d_ws;   // also AO (aliased)
    unsigned short* Kw  = Qw + N_TOK;
    unsigned short* Vt  = Kw + N_TOK;              // transposed V

    const dim3 gg(8, 128);   // N/64 x M/64
    const dim3 ag(32, 32);   // q-tiles x (b*h)
    const float SCALE_Q = 0.1875f;   // 1.5 / sqrt(64)

    // ---- s2e: skel queries attend over sens kv -> output slot 1 ----
    gemm_qkv<<<gg, 256, 0, stream>>>(skel, Wq_s2e, Qw, SCALE_Q);
    gemm_qkv<<<gg, 256, 0, stream>>>(sens, Wk_e,  Kw, 1.0f);
    gemm_vt <<<gg, 256, 0, stream>>>(sens, Wv_e,  Vt);
    attn_mfma<<<ag, 256, 0, stream>>>(Qw, Kw, Vt, mask_sens, Qw);
    gemm_out<<<gg, 256, 0, stream>>>(Qw, Wo_e, out + N_TOK);

    // ---- e2s: sens queries attend over skel kv -> output slot 0 ----
    gemm_qkv<<<gg, 256, 0, stream>>>(sens, Wq_e2s, Qw, SCALE_Q);
    gemm_qkv<<<gg, 256, 0, stream>>>(skel, Wk_s,  Kw, 1.0f);
    gemm_vt <<<gg, 256, 0, stream>>>(skel, Wv_s,  Vt);
    attn_mfma<<<ag, 256, 0, stream>>>(Qw, Kw, Vt, mask_skel, Qw);
    gemm_out<<<gg, 256, 0, stream>>>(Qw, Wo_s, out);
}

// Round 5
// 762.365 us; speedup vs baseline: 4.0344x; 1.8025x over previous
//
#include <hip/hip_runtime.h>
#include <hip/hip_bf16.h>

// Problem constants: B=4, T=2048, D=512, H=8, DK=64
#define T_SEQ 2048
#define N_TOK 4194304   // 4 * 2048 * 512 elements per [B,T,D] tensor

// Inputs: FLOAT32. Output: FLOAT32, (e2s, s2e) concat.
// Intermediates (d_ws, 24 MB): Qw bf16 [B,T,512] (aliased as AO), Kw bf16
// [B,T,512], Vt bf16 [B,512,T] (transposed V for MFMA B-frags).

typedef float f32x4  __attribute__((ext_vector_type(4)));
typedef short bf16x8 __attribute__((ext_vector_type(8)));

__device__ __forceinline__ unsigned short f2b(float f) {
    __hip_bfloat16 h = __float2bfloat16(f);
    return *reinterpret_cast<unsigned short*>(&h);
}

__device__ __forceinline__ int pack2bf(float lo, float hi) {
    return ((int)f2b(hi) << 16) | (int)f2b(lo);
}

// 8 bf16 (16B) -> bf16x8 frag
__device__ __forceinline__ bf16x8 ldg8(const unsigned short* p) {
    union { int4 i; bf16x8 b; } u;
    u.i = *reinterpret_cast<const int4*>(p);
    return u.b;
}

// ---------------------------------------------------------------------------
// MFMA GEMM: C[m,n] = sum_k A[m,k]*W[n,k], M=8192, N=512, K=512.
// 64x64 tile, BK=64, 256 threads (4 waves), wave w computes rows w*16..+15,
// all 64 cols (4 accumulator tiles). fp32 inputs converted to bf16 during
// LDS staging; next-iter global loads overlap the MFMA loop.
// LDS pitch 72 bf16 (144 B): rows alias 2-way for b128 reads (free, m136).
// ---------------------------------------------------------------------------
#define MF_SETUP                                                               \
    __shared__ short Asm[64][72];                                              \
    __shared__ short Wsm[64][72];                                              \
    const int tid  = threadIdx.x;                                              \
    const int lane = tid & 63;                                                 \
    const int w4   = tid >> 6;                                                 \
    const int nl   = lane & 15;                                                \
    const int quad = lane >> 4;                                                \
    const int n0 = blockIdx.x * 64;                                            \
    const int m0 = blockIdx.y * 64;                                            \
    const int arow = tid >> 2;                                                 \
    const int acol = (tid & 3) * 16;                                           \
    f32x4 acc[4] = {};

#define MF_WRITE_W                                                             \
    {                                                                          \
        int4 x;                                                                \
        x.x = pack2bf(wv[0].x, wv[0].y); x.y = pack2bf(wv[0].z, wv[0].w);      \
        x.z = pack2bf(wv[1].x, wv[1].y); x.w = pack2bf(wv[1].z, wv[1].w);      \
        *reinterpret_cast<int4*>(&Wsm[arow][acol]) = x;                        \
        x.x = pack2bf(wv[2].x, wv[2].y); x.y = pack2bf(wv[2].z, wv[2].w);      \
        x.z = pack2bf(wv[3].x, wv[3].y); x.w = pack2bf(wv[3].z, wv[3].w);      \
        *reinterpret_cast<int4*>(&Wsm[arow][acol + 8]) = x;                    \
    }

#define MF_MMA_LOOP                                                            \
    _Pragma("unroll")                                                          \
    for (int kc = 0; kc < 2; ++kc) {                                           \
        const bf16x8 a = *reinterpret_cast<const bf16x8*>(                     \
            &Asm[w4 * 16 + nl][kc * 32 + quad * 8]);                           \
        _Pragma("unroll")                                                      \
        for (int c = 0; c < 4; ++c) {                                          \
            const bf16x8 bf = *reinterpret_cast<const bf16x8*>(                \
                &Wsm[c * 16 + nl][kc * 32 + quad * 8]);                        \
            acc[c] = __builtin_amdgcn_mfma_f32_16x16x32_bf16(a, bf, acc[c],    \
                                                             0, 0, 0);         \
        }                                                                      \
    }

// fp32-A main loop (Q/K/V projections + Vt)
#define MF_MAIN_F32A                                                           \
    MF_SETUP                                                                   \
    const float* ap = A + (size_t)(m0 + arow) * 512 + acol;                    \
    const float* wp = W + (size_t)(n0 + arow) * 512 + acol;                    \
    float4 av[4], wv[4];                                                       \
    _Pragma("unroll")                                                          \
    for (int j = 0; j < 4; ++j) {                                              \
        av[j] = *reinterpret_cast<const float4*>(ap + 4 * j);                  \
        wv[j] = *reinterpret_cast<const float4*>(wp + 4 * j);                  \
    }                                                                          \
    for (int it = 0; it < 8; ++it) {                                           \
        __syncthreads();                                                       \
        {                                                                      \
            int4 x;                                                            \
            x.x = pack2bf(av[0].x, av[0].y); x.y = pack2bf(av[0].z, av[0].w);  \
            x.z = pack2bf(av[1].x, av[1].y); x.w = pack2bf(av[1].z, av[1].w);  \
            *reinterpret_cast<int4*>(&Asm[arow][acol]) = x;                    \
            x.x = pack2bf(av[2].x, av[2].y); x.y = pack2bf(av[2].z, av[2].w);  \
            x.z = pack2bf(av[3].x, av[3].y); x.w = pack2bf(av[3].z, av[3].w);  \
            *reinterpret_cast<int4*>(&Asm[arow][acol + 8]) = x;                \
        }                                                                      \
        MF_WRITE_W                                                             \
        __syncthreads();                                                       \
        if (it < 7) {                                                          \
            const float* apn = ap + (it + 1) * 64;                             \
            const float* wpn = wp + (it + 1) * 64;                             \
            _Pragma("unroll")                                                  \
            for (int j = 0; j < 4; ++j) {                                      \
                av[j] = *reinterpret_cast<const float4*>(apn + 4 * j);         \
                wv[j] = *reinterpret_cast<const float4*>(wpn + 4 * j);         \
            }                                                                  \
        }                                                                      \
        MF_MMA_LOOP                                                            \
    }

// Q/K projection: C bf16 [token][512], scaled by alpha.
__global__ __launch_bounds__(256)
void gemm_qkv(const float* __restrict__ A,
              const float* __restrict__ W,
              unsigned short* __restrict__ C,
              float alpha)
{
    MF_MAIN_F32A
    #pragma unroll
    for (int c = 0; c < 4; ++c)
        #pragma unroll
        for (int r = 0; r < 4; ++r)
            C[(size_t)(m0 + w4 * 16 + quad * 4 + r) * 512 + n0 + c * 16 + nl] =
                f2b(acc[c][r] * alpha);
}

// V projection with transposed epilogue: Vt[b][n=512][t=2048] bf16.
__global__ __launch_bounds__(256)
void gemm_vt(const float* __restrict__ A,
             const float* __restrict__ W,
             unsigned short* __restrict__ Vt)
{
    MF_MAIN_F32A
    const int b  = m0 >> 11;
    const int t0 = (m0 & 2047) + w4 * 16 + quad * 4;
    #pragma unroll
    for (int c = 0; c < 4; ++c) {
        const int n = n0 + c * 16 + nl;
        ushort4 o;
        o.x = f2b(acc[c][0]);
        o.y = f2b(acc[c][1]);
        o.z = f2b(acc[c][2]);
        o.w = f2b(acc[c][3]);
        *reinterpret_cast<ushort4*>(Vt + (size_t)(b * 512 + n) * T_SEQ + t0) = o;
    }
}

// Output projection: A bf16 (AO), W fp32, C fp32.
__global__ __launch_bounds__(256)
void gemm_out(const unsigned short* __restrict__ A,
              const float* __restrict__ W,
              float* __restrict__ C)
{
    MF_SETUP
    const unsigned short* ap = A + (size_t)(m0 + arow) * 512 + acol;
    const float* wp = W + (size_t)(n0 + arow) * 512 + acol;
    int4 ai[2];
    float4 wv[4];
    ai[0] = *reinterpret_cast<const int4*>(ap);
    ai[1] = *reinterpret_cast<const int4*>(ap + 8);
    #pragma unroll
    for (int j = 0; j < 4; ++j)
        wv[j] = *reinterpret_cast<const float4*>(wp + 4 * j);
    for (int it = 0; it < 8; ++it) {
        __syncthreads();
        *reinterpret_cast<int4*>(&Asm[arow][acol])     = ai[0];
        *reinterpret_cast<int4*>(&Asm[arow][acol + 8]) = ai[1];
        MF_WRITE_W
        __syncthreads();
        if (it < 7) {
            const unsigned short* apn = ap + (it + 1) * 64;
            const float* wpn = wp + (it + 1) * 64;
            ai[0] = *reinterpret_cast<const int4*>(apn);
            ai[1] = *reinterpret_cast<const int4*>(apn + 8);
            #pragma unroll
            for (int j = 0; j < 4; ++j)
                wv[j] = *reinterpret_cast<const float4*>(wpn + 4 * j);
        }
        MF_MMA_LOOP
    }
    #pragma unroll
    for (int c = 0; c < 4; ++c)
        #pragma unroll
        for (int r = 0; r < 4; ++r)
            C[(size_t)(m0 + w4 * 16 + quad * 4 + r) * 512 + n0 + c * 16 + nl] =
                acc[c][r];
}

// ---------------------------------------------------------------------------
// MFMA flash attention. Block = 4 waves = one (b,h,64-row q-tile); wave owns
// 16 q rows. S^T = K·Q^T (C-layout col = q), softmax via shfl_xor(16/32);
// P relayout via wave-private LDS. K-frags double-buffered in registers
// (prefetch kt+1); V loads issued at iter top (consumed after softmax);
// mask staged in LDS once. AO may alias Q.
// ---------------------------------------------------------------------------
__global__ __launch_bounds__(256)
void attn_mfma(const unsigned short* Q,
               const unsigned short* __restrict__ K,
               const unsigned short* __restrict__ Vt,
               const int* __restrict__ mask,
               unsigned short* AO)
{
    __shared__ short Pl[4][16][72];
    __shared__ int   mlds[T_SEQ];

    const int tid  = threadIdx.x;
    const int w    = tid >> 6;
    const int lane = tid & 63;
    const int nl   = lane & 15;
    const int quad = lane >> 4;
    const int qt = blockIdx.x;        // 0..31
    const int bh = blockIdx.y;        // 0..31
    const int b = bh >> 3, h = bh & 7;
    const size_t tb = (size_t)b * (T_SEQ * 512);

    // stage mask row for this batch
    {
        const int* mrow = mask + b * T_SEQ;
        *reinterpret_cast<int4*>(&mlds[tid * 8])     = *reinterpret_cast<const int4*>(&mrow[tid * 8]);
        *reinterpret_cast<int4*>(&mlds[tid * 8 + 4]) = *reinterpret_cast<const int4*>(&mrow[tid * 8 + 4]);
    }
    __syncthreads();

    // Q B-frags (n=lane&15 => q row, k=quad*8+j)
    const unsigned short* qp = Q + tb + (size_t)(qt * 64 + w * 16 + nl) * 512 + h * 64 + quad * 8;
    const bf16x8 qb0 = ldg8(qp);
    const bf16x8 qb1 = ldg8(qp + 32);

    float m_run = -INFINITY, l_run = 0.0f;
    f32x4 o[4] = {};   // o[sd]: d = sd*16+nl (col), q = quad*4+reg (row)

    // K A-frag double buffer; prologue loads kt=0
    bf16x8 ka[2][4][2];
    #pragma unroll
    for (int s = 0; s < 4; ++s) {
        const unsigned short* kp = K + tb + (size_t)(s * 16 + nl) * 512 + h * 64 + quad * 8;
        ka[0][s][0] = ldg8(kp);
        ka[0][s][1] = ldg8(kp + 32);
    }

    #pragma unroll 2
    for (int kt = 0; kt < 32; ++kt) {
        const int cur = kt & 1, nxt = cur ^ 1;

        // V B-frags for this tile (consumed after softmax — latency covered)
        bf16x8 vb[4][2];
        #pragma unroll
        for (int sd = 0; sd < 4; ++sd) {
            const unsigned short* vp = Vt + (size_t)(b * 512 + h * 64 + sd * 16 + nl) * T_SEQ + kt * 64 + quad * 8;
            vb[sd][0] = ldg8(vp);
            vb[sd][1] = ldg8(vp + 32);
        }
        // prefetch next K tile
        if (kt < 31) {
            #pragma unroll
            for (int s = 0; s < 4; ++s) {
                const unsigned short* kp = K + tb + (size_t)((kt + 1) * 64 + s * 16 + nl) * 512 + h * 64 + quad * 8;
                ka[nxt][s][0] = ldg8(kp);
                ka[nxt][s][1] = ldg8(kp + 32);
            }
        }

        // scores S^T[kv][q]
        float p[4][4];
        float mx = -INFINITY;
        #pragma unroll
        for (int s = 0; s < 4; ++s) {
            f32x4 z = {};
            z = __builtin_amdgcn_mfma_f32_16x16x32_bf16(ka[cur][s][0], qb0, z, 0, 0, 0);
            z = __builtin_amdgcn_mfma_f32_16x16x32_bf16(ka[cur][s][1], qb1, z, 0, 0, 0);
            const int4 mm = *reinterpret_cast<const int4*>(&mlds[kt * 64 + s * 16 + quad * 4]);
            p[s][0] = (mm.x != 0) ? z[0] : -1e30f;
            p[s][1] = (mm.y != 0) ? z[1] : -1e30f;
            p[s][2] = (mm.z != 0) ? z[2] : -1e30f;
            p[s][3] = (mm.w != 0) ? z[3] : -1e30f;
            #pragma unroll
            for (int r = 0; r < 4; ++r) mx = fmaxf(mx, p[s][r]);
        }

        // online softmax over kv
        mx = fmaxf(mx, __shfl_xor(mx, 16));
        mx = fmaxf(mx, __shfl_xor(mx, 32));
        const float m_new = fmaxf(m_run, mx);
        const float al = __expf(m_run - m_new);
        float ps = 0.0f;
        #pragma unroll
        for (int s = 0; s < 4; ++s)
            #pragma unroll
            for (int r = 0; r < 4; ++r) {
                p[s][r] = __expf(p[s][r] - m_new);
                ps += p[s][r];
            }
        ps += __shfl_xor(ps, 16);
        ps += __shfl_xor(ps, 32);
        l_run = al * l_run + ps;
        m_run = m_new;

        // P: C-layout -> LDS [q][kv] (wave-private, wave-synchronous)
        #pragma unroll
        for (int s = 0; s < 4; ++s) {
            int2 pk;
            pk.x = pack2bf(p[s][0], p[s][1]);
            pk.y = pack2bf(p[s][2], p[s][3]);
            *reinterpret_cast<int2*>(&Pl[w][nl][s * 16 + quad * 4]) = pk;
        }

        // rescale O (alpha lives at lane q; O rows q=quad*4+r)
        const float a0 = __shfl(al, quad * 4 + 0);
        const float a1 = __shfl(al, quad * 4 + 1);
        const float a2 = __shfl(al, quad * 4 + 2);
        const float a3 = __shfl(al, quad * 4 + 3);
        #pragma unroll
        for (int sd = 0; sd < 4; ++sd) {
            o[sd][0] *= a0; o[sd][1] *= a1; o[sd][2] *= a2; o[sd][3] *= a3;
        }

        // P A-frags from LDS, O += P · V
        const bf16x8 pa0 = *reinterpret_cast<const bf16x8*>(&Pl[w][nl][quad * 8]);
        const bf16x8 pa1 = *reinterpret_cast<const bf16x8*>(&Pl[w][nl][32 + quad * 8]);
        #pragma unroll
        for (int sd = 0; sd < 4; ++sd) {
            o[sd] = __builtin_amdgcn_mfma_f32_16x16x32_bf16(pa0, vb[sd][0], o[sd], 0, 0, 0);
            o[sd] = __builtin_amdgcn_mfma_f32_16x16x32_bf16(pa1, vb[sd][1], o[sd], 0, 0, 0);
        }
    }

    // epilogue: AO[q][d] = O/l, bf16
    const float i0 = 1.0f / __shfl(l_run, quad * 4 + 0);
    const float i1 = 1.0f / __shfl(l_run, quad * 4 + 1);
    const float i2 = 1.0f / __shfl(l_run, quad * 4 + 2);
    const float i3 = 1.0f / __shfl(l_run, quad * 4 + 3);
    unsigned short* ob = AO + tb + (size_t)(qt * 64 + w * 16 + quad * 4) * 512 + h * 64 + nl;
    #pragma unroll
    for (int sd = 0; sd < 4; ++sd) {
        ob[0 * 512 + sd * 16] = f2b(o[sd][0] * i0);
        ob[1 * 512 + sd * 16] = f2b(o[sd][1] * i1);
        ob[2 * 512 + sd * 16] = f2b(o[sd][2] * i2);
        ob[3 * 512 + sd * 16] = f2b(o[sd][3] * i3);
    }
}

extern "C" void kernel_launch(void* const* d_in, const int* in_sizes, int n_in,
                              void* d_out, int out_size, void* d_ws, size_t ws_size,
                              hipStream_t stream) {
    const float* skel = (const float*)d_in[0];
    const float* sens = (const float*)d_in[1];
    const int* mask_skel = (const int*)d_in[2];
    const int* mask_sens = (const int*)d_in[3];
    const float* Wq_s2e = (const float*)d_in[4];
    const float* Wk_e   = (const float*)d_in[5];
    const float* Wv_e   = (const float*)d_in[6];
    const float* Wq_e2s = (const float*)d_in[7];
    const float* Wk_s   = (const float*)d_in[8];
    const float* Wv_s   = (const float*)d_in[9];
    const float* Wo_s   = (const float*)d_in[10];
    const float* Wo_e   = (const float*)d_in[11];
    float* out = (float*)d_out;   // fp32: [e2s (4M)][s2e (4M)]

    unsigned short* Qw  = (unsigned short*)d_ws;   // also AO (aliased)
    unsigned short* Kw  = Qw + N_TOK;
    unsigned short* Vt  = Kw + N_TOK;              // transposed V

    const dim3 gg(8, 128);   // N/64 x M/64
    const dim3 ag(32, 32);   // q-tiles x (b*h)
    const float SCALE_Q = 0.1875f;   // 1.5 / sqrt(64)

    // ---- s2e: skel queries attend over sens kv -> output slot 1 ----
    gemm_qkv<<<gg, 256, 0, stream>>>(skel, Wq_s2e, Qw, SCALE_Q);
    gemm_qkv<<<gg, 256, 0, stream>>>(sens, Wk_e,  Kw, 1.0f);
    gemm_vt <<<gg, 256, 0, stream>>>(sens, Wv_e,  Vt);
    attn_mfma<<<ag, 256, 0, stream>>>(Qw, Kw, Vt, mask_sens, Qw);
    gemm_out<<<gg, 256, 0, stream>>>(Qw, Wo_e, out + N_TOK);

    // ---- e2s: sens queries attend over skel kv -> output slot 0 ----
    gemm_qkv<<<gg, 256, 0, stream>>>(sens, Wq_e2s, Qw, SCALE_Q);
    gemm_qkv<<<gg, 256, 0, stream>>>(skel, Wk_s,  Kw, 1.0f);
    gemm_vt <<<gg, 256, 0, stream>>>(skel, Wv_s,  Vt);
    attn_mfma<<<ag, 256, 0, stream>>>(Qw, Kw, Vt, mask_skel, Qw);
    gemm_out<<<gg, 256, 0, stream>>>(Qw, Wo_s, out);
}

// Round 6
// 732.902 us; speedup vs baseline: 4.1965x; 1.0402x over previous
//
#include <hip/hip_runtime.h>
#include <hip/hip_bf16.h>

// Problem constants: B=4, T=2048, D=512, H=8, DK=64
#define T_SEQ 2048
#define N_TOK 4194304   // 4 * 2048 * 512 elements per [B,T,D] tensor

// Inputs: FLOAT32. Output: FLOAT32, (e2s, s2e) concat.
// ws (fused path, 48 MB): Q1,K1 [B,T,512] bf16; Vt1 [B,512,T] bf16; Q2,K2,Vt2.
// AO aliases Q per direction. Fallback (<48 MB ws): 24 MB, sequential.

typedef float f32x4  __attribute__((ext_vector_type(4)));
typedef short bf16x8 __attribute__((ext_vector_type(8)));

#define SCALE_Q 0.1875f   // 1.5 / sqrt(64)

__device__ __forceinline__ unsigned short f2b(float f) {
    __hip_bfloat16 h = __float2bfloat16(f);
    return *reinterpret_cast<unsigned short*>(&h);
}

__device__ __forceinline__ int pack2bf(float lo, float hi) {
    return ((int)f2b(hi) << 16) | (int)f2b(lo);
}

__device__ __forceinline__ bf16x8 ldg8(const unsigned short* p) {
    union { int4 i; bf16x8 b; } u;
    u.i = *reinterpret_cast<const int4*>(p);
    return u.b;
}

// ---------------------------------------------------------------------------
// Shared MFMA-GEMM tile machinery: 64x64 tile, BK=64, 256 threads (4 waves),
// wave w computes rows w*16..+15 x all 64 cols. LDS pitch 72 bf16.
// ---------------------------------------------------------------------------
#define MF_SETUP                                                               \
    __shared__ short Asm[64][72];                                              \
    __shared__ short Wsm[64][72];                                              \
    const int tid  = threadIdx.x;                                              \
    const int lane = tid & 63;                                                 \
    const int w4   = tid >> 6;                                                 \
    const int nl   = lane & 15;                                                \
    const int quad = lane >> 4;                                                \
    const int n0 = blockIdx.x * 64;                                            \
    const int m0 = blockIdx.y * 64;                                            \
    const int arow = tid >> 2;                                                 \
    const int acol = (tid & 3) * 16;                                           \
    f32x4 acc[4] = {};

#define MF_WRITE_W                                                             \
    {                                                                          \
        int4 x;                                                                \
        x.x = pack2bf(wv[0].x, wv[0].y); x.y = pack2bf(wv[0].z, wv[0].w);      \
        x.z = pack2bf(wv[1].x, wv[1].y); x.w = pack2bf(wv[1].z, wv[1].w);      \
        *reinterpret_cast<int4*>(&Wsm[arow][acol]) = x;                        \
        x.x = pack2bf(wv[2].x, wv[2].y); x.y = pack2bf(wv[2].z, wv[2].w);      \
        x.z = pack2bf(wv[3].x, wv[3].y); x.w = pack2bf(wv[3].z, wv[3].w);      \
        *reinterpret_cast<int4*>(&Wsm[arow][acol + 8]) = x;                    \
    }

#define MF_MMA_LOOP                                                            \
    _Pragma("unroll")                                                          \
    for (int kc = 0; kc < 2; ++kc) {                                           \
        const bf16x8 a = *reinterpret_cast<const bf16x8*>(                     \
            &Asm[w4 * 16 + nl][kc * 32 + quad * 8]);                           \
        _Pragma("unroll")                                                      \
        for (int c = 0; c < 4; ++c) {                                          \
            const bf16x8 bf = *reinterpret_cast<const bf16x8*>(                \
                &Wsm[c * 16 + nl][kc * 32 + quad * 8]);                        \
            acc[c] = __builtin_amdgcn_mfma_f32_16x16x32_bf16(a, bf, acc[c],    \
                                                             0, 0, 0);         \
        }                                                                      \
    }

// ---------------------------------------------------------------------------
// All six input projections in one dispatch. z = zbase + blockIdx.z:
//  0: Q1 = skel·Wq1 * SCALE   1: K1 = sens·Wk1   2: Vt1 = (sens·Wv1)^T
//  3: Q2 = sens·Wq2 * SCALE   4: K2 = skel·Wk2   5: Vt2 = (skel·Wv2)^T
// ---------------------------------------------------------------------------
__global__ __launch_bounds__(256)
void proj_all(const float* __restrict__ skel, const float* __restrict__ sens,
              const float* __restrict__ Wq1, const float* __restrict__ Wk1,
              const float* __restrict__ Wv1, const float* __restrict__ Wq2,
              const float* __restrict__ Wk2, const float* __restrict__ Wv2,
              unsigned short* __restrict__ Q1, unsigned short* __restrict__ K1,
              unsigned short* __restrict__ Vt1, unsigned short* __restrict__ Q2,
              unsigned short* __restrict__ K2, unsigned short* __restrict__ Vt2,
              int zbase)
{
    const int z = zbase + blockIdx.z;
    const float* A; const float* W; unsigned short* C;
    float alpha = 1.0f; bool trans = false;
    switch (z) {
        case 0:  A = skel; W = Wq1; C = Q1; alpha = SCALE_Q; break;
        case 1:  A = sens; W = Wk1; C = K1; break;
        case 2:  A = sens; W = Wv1; C = Vt1; trans = true; break;
        case 3:  A = sens; W = Wq2; C = Q2; alpha = SCALE_Q; break;
        case 4:  A = skel; W = Wk2; C = K2; break;
        default: A = skel; W = Wv2; C = Vt2; trans = true; break;
    }

    MF_SETUP
    const float* ap = A + (size_t)(m0 + arow) * 512 + acol;
    const float* wp = W + (size_t)(n0 + arow) * 512 + acol;
    float4 av[4], wv[4];
    #pragma unroll
    for (int j = 0; j < 4; ++j) {
        av[j] = *reinterpret_cast<const float4*>(ap + 4 * j);
        wv[j] = *reinterpret_cast<const float4*>(wp + 4 * j);
    }
    for (int it = 0; it < 8; ++it) {
        __syncthreads();
        {
            int4 x;
            x.x = pack2bf(av[0].x, av[0].y); x.y = pack2bf(av[0].z, av[0].w);
            x.z = pack2bf(av[1].x, av[1].y); x.w = pack2bf(av[1].z, av[1].w);
            *reinterpret_cast<int4*>(&Asm[arow][acol]) = x;
            x.x = pack2bf(av[2].x, av[2].y); x.y = pack2bf(av[2].z, av[2].w);
            x.z = pack2bf(av[3].x, av[3].y); x.w = pack2bf(av[3].z, av[3].w);
            *reinterpret_cast<int4*>(&Asm[arow][acol + 8]) = x;
        }
        MF_WRITE_W
        __syncthreads();
        if (it < 7) {
            const float* apn = ap + (it + 1) * 64;
            const float* wpn = wp + (it + 1) * 64;
            #pragma unroll
            for (int j = 0; j < 4; ++j) {
                av[j] = *reinterpret_cast<const float4*>(apn + 4 * j);
                wv[j] = *reinterpret_cast<const float4*>(wpn + 4 * j);
            }
        }
        MF_MMA_LOOP
    }

    if (!trans) {
        #pragma unroll
        for (int c = 0; c < 4; ++c)
            #pragma unroll
            for (int r = 0; r < 4; ++r)
                C[(size_t)(m0 + w4 * 16 + quad * 4 + r) * 512 + n0 + c * 16 + nl] =
                    f2b(acc[c][r] * alpha);
    } else {
        const int b  = m0 >> 11;
        const int t0 = (m0 & 2047) + w4 * 16 + quad * 4;
        #pragma unroll
        for (int c = 0; c < 4; ++c) {
            const int n = n0 + c * 16 + nl;
            ushort4 o;
            o.x = f2b(acc[c][0]);
            o.y = f2b(acc[c][1]);
            o.z = f2b(acc[c][2]);
            o.w = f2b(acc[c][3]);
            *reinterpret_cast<ushort4*>(C + (size_t)(b * 512 + n) * T_SEQ + t0) = o;
        }
    }
}

// ---------------------------------------------------------------------------
// Both output projections in one dispatch. z = zbase + blockIdx.z:
//  0: out1 = AO1·Wo1   1: out2 = AO2·Wo2      (A bf16, W fp32, C fp32)
// ---------------------------------------------------------------------------
__global__ __launch_bounds__(256)
void out_proj(const unsigned short* __restrict__ AO1, const float* __restrict__ Wo1,
              float* __restrict__ C1,
              const unsigned short* __restrict__ AO2, const float* __restrict__ Wo2,
              float* __restrict__ C2, int zbase)
{
    const int z = zbase + blockIdx.z;
    const unsigned short* A = z ? AO2 : AO1;
    const float* W = z ? Wo2 : Wo1;
    float* C = z ? C2 : C1;

    MF_SETUP
    const unsigned short* ap = A + (size_t)(m0 + arow) * 512 + acol;
    const float* wp = W + (size_t)(n0 + arow) * 512 + acol;
    int4 ai[2];
    float4 wv[4];
    ai[0] = *reinterpret_cast<const int4*>(ap);
    ai[1] = *reinterpret_cast<const int4*>(ap + 8);
    #pragma unroll
    for (int j = 0; j < 4; ++j)
        wv[j] = *reinterpret_cast<const float4*>(wp + 4 * j);
    for (int it = 0; it < 8; ++it) {
        __syncthreads();
        *reinterpret_cast<int4*>(&Asm[arow][acol])     = ai[0];
        *reinterpret_cast<int4*>(&Asm[arow][acol + 8]) = ai[1];
        MF_WRITE_W
        __syncthreads();
        if (it < 7) {
            const unsigned short* apn = ap + (it + 1) * 64;
            const float* wpn = wp + (it + 1) * 64;
            ai[0] = *reinterpret_cast<const int4*>(apn);
            ai[1] = *reinterpret_cast<const int4*>(apn + 8);
            #pragma unroll
            for (int j = 0; j < 4; ++j)
                wv[j] = *reinterpret_cast<const float4*>(wpn + 4 * j);
        }
        MF_MMA_LOOP
    }
    #pragma unroll
    for (int c = 0; c < 4; ++c)
        #pragma unroll
        for (int r = 0; r < 4; ++r)
            C[(size_t)(m0 + w4 * 16 + quad * 4 + r) * 512 + n0 + c * 16 + nl] =
                acc[c][r];
}

// ---------------------------------------------------------------------------
// MFMA flash attention, both directions in one dispatch (blockIdx.y >> 5).
// Block = 4 waves = one (dir,b,h,64-row q-tile); wave owns 16 q rows.
// S^T = K·Q^T (C-layout col=q), softmax via shfl_xor(16/32); P relayout via
// wave-private LDS; K-frags double-buffered in regs; V loads issued early;
// mask staged in LDS. AO aliases Q per direction (block-local RAW only).
// ---------------------------------------------------------------------------
__global__ __launch_bounds__(256)
void attn_mfma(const unsigned short* Q1x, const unsigned short* __restrict__ K1x,
               const unsigned short* __restrict__ V1x, const int* __restrict__ m1x,
               unsigned short* AO1x,
               const unsigned short* Q2x, const unsigned short* __restrict__ K2x,
               const unsigned short* __restrict__ V2x, const int* __restrict__ m2x,
               unsigned short* AO2x)
{
    __shared__ short Pl[4][16][72];
    __shared__ int   mlds[T_SEQ];

    const int dir = blockIdx.y >> 5;
    const unsigned short* Q  = dir ? Q2x : Q1x;
    const unsigned short* K  = dir ? K2x : K1x;
    const unsigned short* Vt = dir ? V2x : V1x;
    const int* mask          = dir ? m2x : m1x;
    unsigned short* AO       = dir ? AO2x : AO1x;

    const int tid  = threadIdx.x;
    const int w    = tid >> 6;
    const int lane = tid & 63;
    const int nl   = lane & 15;
    const int quad = lane >> 4;
    const int qt = blockIdx.x;              // 0..31
    const int bh = blockIdx.y & 31;         // 0..31
    const int b = bh >> 3, h = bh & 7;
    const size_t tb = (size_t)b * (T_SEQ * 512);

    // stage mask row for this batch
    {
        const int* mrow = mask + b * T_SEQ;
        *reinterpret_cast<int4*>(&mlds[tid * 8])     = *reinterpret_cast<const int4*>(&mrow[tid * 8]);
        *reinterpret_cast<int4*>(&mlds[tid * 8 + 4]) = *reinterpret_cast<const int4*>(&mrow[tid * 8 + 4]);
    }
    __syncthreads();

    // Q B-frags (n=lane&15 => q row, k=quad*8+j)
    const unsigned short* qp = Q + tb + (size_t)(qt * 64 + w * 16 + nl) * 512 + h * 64 + quad * 8;
    const bf16x8 qb0 = ldg8(qp);
    const bf16x8 qb1 = ldg8(qp + 32);

    float m_run = -INFINITY, l_run = 0.0f;
    f32x4 o[4] = {};   // o[sd]: d = sd*16+nl (col), q = quad*4+reg (row)

    // K A-frag double buffer; prologue loads kt=0
    bf16x8 ka[2][4][2];
    #pragma unroll
    for (int s = 0; s < 4; ++s) {
        const unsigned short* kp = K + tb + (size_t)(s * 16 + nl) * 512 + h * 64 + quad * 8;
        ka[0][s][0] = ldg8(kp);
        ka[0][s][1] = ldg8(kp + 32);
    }

    #pragma unroll 2
    for (int kt = 0; kt < 32; ++kt) {
        const int cur = kt & 1, nxt = cur ^ 1;

        // V B-frags for this tile (consumed after softmax)
        bf16x8 vb[4][2];
        #pragma unroll
        for (int sd = 0; sd < 4; ++sd) {
            const unsigned short* vp = Vt + (size_t)(b * 512 + h * 64 + sd * 16 + nl) * T_SEQ + kt * 64 + quad * 8;
            vb[sd][0] = ldg8(vp);
            vb[sd][1] = ldg8(vp + 32);
        }
        // prefetch next K tile
        if (kt < 31) {
            #pragma unroll
            for (int s = 0; s < 4; ++s) {
                const unsigned short* kp = K + tb + (size_t)((kt + 1) * 64 + s * 16 + nl) * 512 + h * 64 + quad * 8;
                ka[nxt][s][0] = ldg8(kp);
                ka[nxt][s][1] = ldg8(kp + 32);
            }
        }

        // scores S^T[kv][q]
        float p[4][4];
        float mx = -INFINITY;
        #pragma unroll
        for (int s = 0; s < 4; ++s) {
            f32x4 z = {};
            z = __builtin_amdgcn_mfma_f32_16x16x32_bf16(ka[cur][s][0], qb0, z, 0, 0, 0);
            z = __builtin_amdgcn_mfma_f32_16x16x32_bf16(ka[cur][s][1], qb1, z, 0, 0, 0);
            const int4 mm = *reinterpret_cast<const int4*>(&mlds[kt * 64 + s * 16 + quad * 4]);
            p[s][0] = (mm.x != 0) ? z[0] : -1e30f;
            p[s][1] = (mm.y != 0) ? z[1] : -1e30f;
            p[s][2] = (mm.z != 0) ? z[2] : -1e30f;
            p[s][3] = (mm.w != 0) ? z[3] : -1e30f;
            #pragma unroll
            for (int r = 0; r < 4; ++r) mx = fmaxf(mx, p[s][r]);
        }

        // online softmax over kv
        mx = fmaxf(mx, __shfl_xor(mx, 16));
        mx = fmaxf(mx, __shfl_xor(mx, 32));
        const float m_new = fmaxf(m_run, mx);
        const float al = __expf(m_run - m_new);
        float ps = 0.0f;
        #pragma unroll
        for (int s = 0; s < 4; ++s)
            #pragma unroll
            for (int r = 0; r < 4; ++r) {
                p[s][r] = __expf(p[s][r] - m_new);
                ps += p[s][r];
            }
        ps += __shfl_xor(ps, 16);
        ps += __shfl_xor(ps, 32);
        l_run = al * l_run + ps;
        m_run = m_new;

        // P: C-layout -> LDS [q][kv] (wave-private, wave-synchronous)
        #pragma unroll
        for (int s = 0; s < 4; ++s) {
            int2 pk;
            pk.x = pack2bf(p[s][0], p[s][1]);
            pk.y = pack2bf(p[s][2], p[s][3]);
            *reinterpret_cast<int2*>(&Pl[w][nl][s * 16 + quad * 4]) = pk;
        }

        // rescale O (alpha lives at lane q; O rows q=quad*4+r)
        const float a0 = __shfl(al, quad * 4 + 0);
        const float a1 = __shfl(al, quad * 4 + 1);
        const float a2 = __shfl(al, quad * 4 + 2);
        const float a3 = __shfl(al, quad * 4 + 3);
        #pragma unroll
        for (int sd = 0; sd < 4; ++sd) {
            o[sd][0] *= a0; o[sd][1] *= a1; o[sd][2] *= a2; o[sd][3] *= a3;
        }

        // P A-frags from LDS, O += P · V
        const bf16x8 pa0 = *reinterpret_cast<const bf16x8*>(&Pl[w][nl][quad * 8]);
        const bf16x8 pa1 = *reinterpret_cast<const bf16x8*>(&Pl[w][nl][32 + quad * 8]);
        #pragma unroll
        for (int sd = 0; sd < 4; ++sd) {
            o[sd] = __builtin_amdgcn_mfma_f32_16x16x32_bf16(pa0, vb[sd][0], o[sd], 0, 0, 0);
            o[sd] = __builtin_amdgcn_mfma_f32_16x16x32_bf16(pa1, vb[sd][1], o[sd], 0, 0, 0);
        }
    }

    // epilogue: AO[q][d] = O/l, bf16
    const float i0 = 1.0f / __shfl(l_run, quad * 4 + 0);
    const float i1 = 1.0f / __shfl(l_run, quad * 4 + 1);
    const float i2 = 1.0f / __shfl(l_run, quad * 4 + 2);
    const float i3 = 1.0f / __shfl(l_run, quad * 4 + 3);
    unsigned short* ob = AO + tb + (size_t)(qt * 64 + w * 16 + quad * 4) * 512 + h * 64 + nl;
    #pragma unroll
    for (int sd = 0; sd < 4; ++sd) {
        ob[0 * 512 + sd * 16] = f2b(o[sd][0] * i0);
        ob[1 * 512 + sd * 16] = f2b(o[sd][1] * i1);
        ob[2 * 512 + sd * 16] = f2b(o[sd][2] * i2);
        ob[3 * 512 + sd * 16] = f2b(o[sd][3] * i3);
    }
}

extern "C" void kernel_launch(void* const* d_in, const int* in_sizes, int n_in,
                              void* d_out, int out_size, void* d_ws, size_t ws_size,
                              hipStream_t stream) {
    const float* skel = (const float*)d_in[0];
    const float* sens = (const float*)d_in[1];
    const int* mask_skel = (const int*)d_in[2];
    const int* mask_sens = (const int*)d_in[3];
    const float* Wq_s2e = (const float*)d_in[4];
    const float* Wk_e   = (const float*)d_in[5];
    const float* Wv_e   = (const float*)d_in[6];
    const float* Wq_e2s = (const float*)d_in[7];
    const float* Wk_s   = (const float*)d_in[8];
    const float* Wv_s   = (const float*)d_in[9];
    const float* Wo_s   = (const float*)d_in[10];
    const float* Wo_e   = (const float*)d_in[11];
    float* out = (float*)d_out;   // fp32: [e2s (4M)][s2e (4M)]

    unsigned short* Q1 = (unsigned short*)d_ws;    // dir0 Q / AO (aliased)
    unsigned short* K1 = Q1 + N_TOK;
    unsigned short* V1 = K1 + N_TOK;               // Vt

    const bool big = ws_size >= (size_t)6 * N_TOK * sizeof(unsigned short);

    if (big) {
        unsigned short* Q2 = V1 + N_TOK;
        unsigned short* K2 = Q2 + N_TOK;
        unsigned short* V2 = K2 + N_TOK;
        // dir0 = s2e (out slot 1), dir1 = e2s (out slot 0)
        proj_all<<<dim3(8, 128, 6), 256, 0, stream>>>(
            skel, sens, Wq_s2e, Wk_e, Wv_e, Wq_e2s, Wk_s, Wv_s,
            Q1, K1, V1, Q2, K2, V2, 0);
        attn_mfma<<<dim3(32, 64), 256, 0, stream>>>(
            Q1, K1, V1, mask_sens, Q1,
            Q2, K2, V2, mask_skel, Q2);
        out_proj<<<dim3(8, 128, 2), 256, 0, stream>>>(
            Q1, Wo_e, out + N_TOK, Q2, Wo_s, out, 0);
    } else {
        // sequential fallback: reuse the 3-buffer workspace per direction
        proj_all<<<dim3(8, 128, 3), 256, 0, stream>>>(
            skel, sens, Wq_s2e, Wk_e, Wv_e, Wq_e2s, Wk_s, Wv_s,
            Q1, K1, V1, Q1, K1, V1, 0);
        attn_mfma<<<dim3(32, 32), 256, 0, stream>>>(
            Q1, K1, V1, mask_sens, Q1, Q1, K1, V1, mask_sens, Q1);
        out_proj<<<dim3(8, 128, 1), 256, 0, stream>>>(
            Q1, Wo_e, out + N_TOK, Q1, Wo_s, out, 0);
        proj_all<<<dim3(8, 128, 3), 256, 0, stream>>>(
            skel, sens, Wq_s2e, Wk_e, Wv_e, Wq_e2s, Wk_s, Wv_s,
            Q1, K1, V1, Q1, K1, V1, 3);
        attn_mfma<<<dim3(32, 32), 256, 0, stream>>>(
            Q1, K1, V1, mask_skel, Q1, Q1, K1, V1, mask_skel, Q1);
        out_proj<<<dim3(8, 128, 1), 256, 0, stream>>>(
            Q1, Wo_s, out, Q1, Wo_s, out, 1);
    }
}